// Round 13
// baseline (171.703 us; speedup 1.0000x reference)
//
#include <hip/hip_runtime.h>
#include <stdint.h>

#define BB    2048
#define DIN   4096
#define DOUT  4096

// ---------------------------------------------------------------------------
// i8 MFMA bit-GEMM. x,m -> ±1 int8; dot± = 2*sums - 4096;
// out = sums > thr  <=>  dot± > 2*thr - 4096. Exact in i32.
//
// R20 post-mortem: best total 170.2 (pack scatter-fix paid; bgemm 50 in its
// usual 45-50 band). Re-accounting: bgemm requests 384 MB of operands
// (1.5MB/block x 256); only 33MB from HBM; the 4m x 8n XCD patch has ~20MB
// working set vs 4MB L2 -> thrash -> ~all 384MB served by L3 fabric at
// ~8-9 TB/s = the pinned ~45us wall. Explains every schedule null (R8-R17),
// R13 (768MB -> 79us), R15 (786MB -> 64us). R21: bm = XCD (flat&7),
// bn = flat>>3. The 32 co-resident blocks per XCD share ONE A panel --
// same 32KB A-chunk each step (1 L3 fetch + 31 L2 hits) -- and stream
// their own 512KB B panel once. L3 traffic 384 -> 139 MB. Two lines of
// index math; all else R20-verbatim.
// Falsifier: bgemm >= 46us -> locality model wrong -> R20 + ROOFLINE.
// ws: x8f frag-major [rb 64][kp 128][1024B] @0 (8 MB);
//     m8Tf frag-major [nb 128][kp 128][1024B] @8MB (16 MB).
// chunk(rb,kp): rows rb*32..+31, k bytes [kp*32,+32); lane l = row l&31,
// k-half l>>5, 16B -- the R7-verified mfma_i32_32x32x32_i8 operand map.
// ---------------------------------------------------------------------------

using v4i  = __attribute__((ext_vector_type(4)))  int;
using v16i = __attribute__((ext_vector_type(16))) int;

__device__ __forceinline__ void async_load16(const void* g, void* l) {
    __builtin_amdgcn_global_load_lds(
        (const __attribute__((address_space(1))) unsigned int*)g,
        (__attribute__((address_space(3))) unsigned int*)l,
        16, 0, 0);
}

// bytes {0,1} -> {+1, -1(0xFF)}; no cross-byte carries.
__device__ __forceinline__ unsigned int to_pm1(unsigned int c) {
    return c + ((c ^ 0x01010101u) * 255u);
}

// Fused packing (R20 verbatim).
// blocks [0,256): x -> x8f. Block (rb = b>>2, kq = b&3): chunk rows rb,
//   kps kq*32..+31. Wave w does kp = kq*32 + w*8 + j; lane l = chunk slot
//   (row rb*32+(l&31), k-half l>>5): 4x int4 contiguous reads -> to_pm1 ->
//   one uint4 store; wave store = one contiguous 1KB chunk.
// blocks [256, 256+1024): 64(n) x 256(k) LDS transpose of masks -> m8Tf.
__global__ void pack_all(const int* __restrict__ x,
                         const void* __restrict__ mraw,
                         char* __restrict__ x8f,
                         char* __restrict__ m8Tf) {
    const int tid = threadIdx.x;
    if (blockIdx.x < 256) {
        const int rb   = blockIdx.x >> 2;          // 0..63
        const int kq   = blockIdx.x & 3;           // kp quarter
        const int lane = tid & 63;
        const int wv   = tid >> 6;                 // 0..3
        const int row  = rb * 32 + (lane & 31);
        const int khw  = (lane >> 5) * 4;          // int4 offset of k-half
        const int4* src = (const int4*)(x + (size_t)row * DIN);
        char* dst0 = x8f + (size_t)rb * 131072 + lane * 16;
        #pragma unroll
        for (int j = 0; j < 8; ++j) {
            const int kp = kq * 32 + wv * 8 + j;
            const int w0 = kp * 8 + khw;           // int4 index in row
            unsigned int t[4];
            #pragma unroll
            for (int q = 0; q < 4; ++q) {
                int4 v = src[w0 + q];              // 16B contiguous/lane
                t[q] = to_pm1((unsigned int)(v.x & 1) |
                              ((unsigned int)(v.y & 1) << 8) |
                              ((unsigned int)(v.z & 1) << 16) |
                              ((unsigned int)(v.w & 1) << 24));
            }
            uint4 U; U.x = t[0]; U.y = t[1]; U.z = t[2]; U.w = t[3];
            *(uint4*)(dst0 + (size_t)kp * 1024) = U;  // wave: 1KB contiguous
        }
    } else {
        const int bw = blockIdx.x - 256;           // 0..1023
        const int n0 = (bw >> 4) * 64;             // 64 n-tiles
        const int k0 = (bw & 15) * 256;            // 16 k-strips of 256

        __shared__ unsigned int tl[64][68];        // [n][k-word], pad 68

        // dtype detect (u8-bool vs int32), exact: int32 words are {0,1};
        // u8-bool words exceed 1 unless bytes 1-3 all zero (P ~ 8^-64/wave).
        const unsigned char* mb = (const unsigned char*)mraw;
        const unsigned int pv = *(const unsigned int*)(mb + (tid & 63) * 4);
        const bool isU8 = __any(pv > 1u);

        // stage 1: thread reads 4 k-rows x 16 n-cols (16B/lane coalesced).
        const int kq4  = tid >> 2;                 // 0..63: k-quad index
        const int nq16 = (tid & 3) * 16;           // n-group base
        unsigned int b[4][4];                      // [k-row r][n-word w]
        if (isU8) {
            #pragma unroll
            for (int r = 0; r < 4; ++r) {
                uint4 v = *(const uint4*)(mb + (size_t)(k0 + kq4 * 4 + r) * DOUT
                                          + n0 + nq16);
                b[r][0] = v.x; b[r][1] = v.y; b[r][2] = v.z; b[r][3] = v.w;
            }
        } else {
            const int4* m32 = (const int4*)mraw;
            #pragma unroll
            for (int r = 0; r < 4; ++r)
                #pragma unroll
                for (int q = 0; q < 4; ++q) {
                    int4 v = m32[((size_t)(k0 + kq4 * 4 + r) * DOUT
                                  + n0 + nq16 + q * 4) >> 2];
                    b[r][q] = (unsigned int)(v.x & 1) |
                              ((unsigned int)(v.y & 1) << 8) |
                              ((unsigned int)(v.z & 1) << 16) |
                              ((unsigned int)(v.w & 1) << 24);
                }
        }
        // transpose each 4x4 byte block via v_perm (verified recipe), ±1,
        // write n-major into LDS: word [n][kq4] = bytes k=k0+kq4*4..+3.
        #pragma unroll
        for (int w = 0; w < 4; ++w) {
            unsigned int a0 = b[0][w], a1 = b[1][w], a2 = b[2][w], a3 = b[3][w];
            unsigned int x0 = __builtin_amdgcn_perm(a1, a0, 0x05010400u);
            unsigned int x1 = __builtin_amdgcn_perm(a3, a2, 0x05010400u);
            unsigned int x2 = __builtin_amdgcn_perm(a1, a0, 0x07030602u);
            unsigned int x3 = __builtin_amdgcn_perm(a3, a2, 0x07030602u);
            unsigned int c0 = __builtin_amdgcn_perm(x1, x0, 0x05040100u);
            unsigned int c1 = __builtin_amdgcn_perm(x1, x0, 0x07060302u);
            unsigned int c2 = __builtin_amdgcn_perm(x3, x2, 0x05040100u);
            unsigned int c3 = __builtin_amdgcn_perm(x3, x2, 0x07060302u);
            tl[nq16 + w * 4 + 0][kq4] = to_pm1(c0);
            tl[nq16 + w * 4 + 1][kq4] = to_pm1(c1);
            tl[nq16 + w * 4 + 2][kq4] = to_pm1(c2);
            tl[nq16 + w * 4 + 3][kq4] = to_pm1(c3);
        }
        __syncthreads();

        // stage 2: frag-major out. Wave wvp writes chunks idx = wvp*4+j:
        // nb-local = idx>>3, kp-local = idx&7. Lane l holds
        // (n = nb*32 + (l&31), k-half l>>5) -> 16B; 64 lanes = 1KB coalesced.
        const int l   = tid & 63;
        const int wvp = tid >> 6;
        #pragma unroll
        for (int j = 0; j < 4; ++j) {
            const int idxc = wvp * 4 + j;          // 0..15
            const int nbl  = idxc >> 3;            // 0..1
            const int kpl  = idxc & 7;             // 0..7
            uint4 v = *(const uint4*)&tl[nbl * 32 + (l & 31)]
                                       [kpl * 8 + (l >> 5) * 4];
            const size_t off = (size_t)((n0 >> 5) + nbl) * 131072 +
                               (size_t)((k0 >> 5) + kpl) * 1024 + l * 16;
            *(uint4*)(m8Tf + off) = v;
        }
    }
}

// i8 MFMA GEMM (R17 schedule; R21 XCD map): 256(m)x128(n) block tile,
// 8 waves = 2m x 2n x 2k(split-K), wave tile 128x64 (acc[4][2]). BK=128
// chunks (32), triple-buffer LDS (144 KB), depth-2 prefetch, one raw
// s_barrier per chunk with counted vmcnt(6). Split-K combine via LDS pool.
// R21 map: bm = flat&7 = XCD, bn = flat>>3 -> each XCD's 32 co-resident
// blocks share one A panel (same 32KB chunk each step) and stream B once:
// L3 traffic 384 -> 139 MB.
__global__ __launch_bounds__(512)
void bgemm(const char* __restrict__ x8f,
           const char* __restrict__ m8Tf,
           const int* __restrict__ thr,
           int* __restrict__ out) {
    const int flat = blockIdx.x;                   // 0..255
    const int bm   = flat & 7;                     // XCD id = A panel
    const int bn   = flat >> 3;                    // 0..31
    const int b0   = bm * 256;                     // m
    const int o0   = bn * 128;                     // n

    const int tid  = threadIdx.x;
    const int lane = tid & 63;
    const int wv   = tid >> 6;           // 0..7
    const int im   = wv & 1;
    const int in_  = (wv >> 1) & 1;
    const int kh   = wv >> 2;            // split-K half
    const int wm   = im * 128;           // wave tile m origin
    const int wn   = in_ * 64;           // wave tile n origin
    const int l31  = lane & 31;
    const int lh   = lane >> 5;

    // 3 buffers x (A 32KB + B 16KB) = 144 KB; pool reused for split-K combine.
    __shared__ __align__(16) char lds[3 * 49152];

    // stage chunk-step c -> buf: 48 x 1KB frag chunks, all linear.
    // 6 global_load_lds per thread (A:4, B:2) -- vmcnt schedule = R11.
    auto stage = [&](int c, int buf) {
        char* bufA = lds + buf * 49152;
        char* bufB = bufA + 32768;
        const int kp0 = c * 4;
        #pragma unroll
        for (int j = 0; j < 4; ++j) {              // A: 4 chunks/wave
            const int ci = wv * 4 + j;             // 0..31
            const int rb = ci >> 2, kp = ci & 3;
            async_load16(x8f + (size_t)(bm * 8 + rb) * 131072 +
                               (size_t)(kp0 + kp) * 1024 + lane * 16,
                         bufA + ci * 1024 + lane * 16);
        }
        #pragma unroll
        for (int j = 0; j < 2; ++j) {              // B: 2 chunks/wave
            const int ci = wv * 2 + j;             // 0..15
            const int nb = ci >> 2, kp = ci & 3;
            async_load16(m8Tf + (size_t)(bn * 4 + nb) * 131072 +
                                (size_t)(kp0 + kp) * 1024 + lane * 16,
                         bufB + ci * 1024 + lane * 16);
        }
    };

    v16i acc[4][2];
    #pragma unroll
    for (int t = 0; t < 4; ++t)
        #pragma unroll
        for (int u = 0; u < 2; ++u)
            acc[t][u] = (v16i)(0);

    // prologue: depth-2 prefetch (12 loads/thread in flight).
    stage(0, 0);
    stage(1, 1);

    for (int c = 0; c < 32; ++c) {
        // drain exactly stage(c): leave stage(c+1) (6 loads) in flight.
        if (c < 31) asm volatile("s_waitcnt vmcnt(6)" ::: "memory");
        else        asm volatile("s_waitcnt vmcnt(0)" ::: "memory");
        __builtin_amdgcn_s_barrier();  // stage(c) visible everywhere; all
                                       // waves done computing c-1 -> buf free
        if (c < 30) stage(c + 2, (c + 2) % 3);

        const char* bufA = lds + (c % 3) * 49152;
        const char* bufB = bufA + 32768;
        #pragma unroll
        for (int ks = 0; ks < 2; ++ks) {
            const int kp = kh * 2 + ks;            // this wave's kp chunk
            v4i aF[4], bF[2];
            #pragma unroll
            for (int t = 0; t < 4; ++t)
                aF[t] = *(const v4i*)&bufA[((im * 4 + t) * 4 + kp) * 1024
                                           + lane * 16];
            #pragma unroll
            for (int u = 0; u < 2; ++u)
                bF[u] = *(const v4i*)&bufB[((in_ * 2 + u) * 4 + kp) * 1024
                                           + lane * 16];
            #pragma unroll
            for (int t = 0; t < 4; ++t)
                #pragma unroll
                for (int u = 0; u < 2; ++u)
                    acc[t][u] = __builtin_amdgcn_mfma_i32_32x32x32_i8(
                        aF[t], bF[u], acc[t][u], 0, 0, 0);
        }
    }
    __syncthreads();   // all compute done; lds pool free for combine

    // ---- split-K combine. Pair p = (im,in_): waves (p, kh=0) and (p, kh=1)
    // computed the same 128x64 tile over disjoint K halves. Each wave gives
    // one 64-row half via LDS and keeps the other: h=0 keeps t0,1 gives t2,3;
    // h=1 keeps t2,3 gives t0,1. Pool: per pair 8192 i32 (2 halves x 4096).
    int* pool = (int*)lds;                         // 128 KB used
    const int p = wv & 3;
    {
        const int give0 = kh ? 0 : 2;              // first given t
        const int bw_ = p * 8192 + (kh ? 0 : 1) * 4096;
        #pragma unroll
        for (int tt = 0; tt < 2; ++tt) {
            const int t = give0 + tt;
            #pragma unroll
            for (int u = 0; u < 2; ++u)
                #pragma unroll
                for (int r = 0; r < 16; ++r) {
                    const int rowl = (r & 3) + 8 * (r >> 2) + 4 * lh;
                    pool[bw_ + (tt * 32 + rowl) * 64 + u * 32 + l31] = acc[t][u][r];
                }
        }
    }
    __syncthreads();
    const int keep0 = kh ? 2 : 0;
    const int br_ = p * 8192 + kh * 4096;          // partner's gift = my kept rows
    #pragma unroll
    for (int tt = 0; tt < 2; ++tt) {
        const int t = keep0 + tt;
        #pragma unroll
        for (int u = 0; u < 2; ++u)
            #pragma unroll
            for (int r = 0; r < 16; ++r) {
                const int rowl = (r & 3) + 8 * (r >> 2) + 4 * lh;
                acc[t][u][r] += pool[br_ + (tt * 32 + rowl) * 64 + u * 32 + l31];
            }
    }

    // epilogue: out = (dot± > 2*thr - 4096).
    // C/D layout (verified R7): col = lane&31; row = (reg&3)+8*(reg>>2)+4*(lane>>5).
    #pragma unroll
    for (int u = 0; u < 2; ++u) {
        const int o   = o0 + wn + u * 32 + l31;
        const int lim = 2 * thr[o] - DIN;
        #pragma unroll
        for (int tt = 0; tt < 2; ++tt) {
            const int t = keep0 + tt;
            #pragma unroll
            for (int r = 0; r < 16; ++r) {
                const int rowl = (r & 3) + 8 * (r >> 2) + 4 * lh;
                const int b    = b0 + wm + kh * 64 + tt * 32 + rowl;
                out[(size_t)b * DOUT + o] = (acc[t][u][r] > lim) ? 1 : 0;
            }
        }
    }
}

extern "C" void kernel_launch(void* const* d_in, const int* in_sizes, int n_in,
                              void* d_out, int out_size, void* d_ws, size_t ws_size,
                              hipStream_t stream) {
    const int* x          = (const int*)d_in[0];
    const void* masks     = d_in[1];           // bool: u8 or int32 (detected inline)
    const int* thresholds = (const int*)d_in[2];
    int* out              = (int*)d_out;

    char* x8f  = (char*)d_ws;                         // 8 MB frag-major
    char* m8Tf = (char*)d_ws + ((size_t)8 << 20);     // 16 MB frag-major

    pack_all<<<256 + 1024, 256, 0, stream>>>(x, masks, x8f, m8Tf);
    bgemm<<<256, 512, 0, stream>>>(x8f, m8Tf, thresholds, out);
}

// Round 14
// 168.996 us; speedup vs baseline: 1.0160x; 1.0160x over previous
//
#include <hip/hip_runtime.h>
#include <stdint.h>

#define BB    2048
#define DIN   4096
#define DOUT  4096

// ---------------------------------------------------------------------------
// i8 MFMA bit-GEMM. x,m -> ±1 int8; dot± = 2*sums - 4096;
// out = sums > thr  <=>  dot± > 2*thr - 4096. Exact in i32.
//
// R21 post-mortem: XCD map doubled FETCH (33->70MB) at unchanged ~45us ->
// fabric volume NOT binding; bgemm pinned 44-50 across all 13 rounds of
// schedule/layout/conflict/traffic changes (LDS||MFMA serialization +
// ~650cyc/chunk rendezvous; 3 phase-split attempts regressed). bgemm frozen
// at R21 (best samples). R22 attacks the modeled gap: pack 43.6us @ 1.75TB/s
// (28% of achievable), VALU 5.5%, occ 30% -> latency/parallelism-bound.
// pack_x: was 256 blks (1 wave/SIMD) with 16B-granule transposed reads;
// now LDS-staged: per-instr a wave reads a CONTIGUOUS 1KB row run (lane l
// = int4 l of a 4KB row fragment), ±1-packs to LDS [32][260]u32, then
// stores verified frag-major chunks as 1KB wave runs. 512thr, 16 unrolled
// loads/thread in flight. pack_m: 512-thr blocks, 2 tiles in parallel
// (half the blocks, 2x waves/block). One dispatch 768x512.
// Predict: pack 43.6 -> 30-36, bgemm 44-45 unchanged, total ~160-166.
// Falsifier: pack >= 41 -> unmodeled floor -> revert + declare ceiling.
// ws: x8f frag-major [rb 64][kp 128][1024B] @0 (8 MB);
//     m8Tf frag-major [nb 128][kp 128][1024B] @8MB (16 MB).
// chunk(rb,kp): rows rb*32..+31, k bytes [kp*32,+32); lane l = row l&31,
// k-half l>>5, 16B -- the R7-verified mfma_i32_32x32x32_i8 operand map.
// ---------------------------------------------------------------------------

using v4i  = __attribute__((ext_vector_type(4)))  int;
using v16i = __attribute__((ext_vector_type(16))) int;

__device__ __forceinline__ void async_load16(const void* g, void* l) {
    __builtin_amdgcn_global_load_lds(
        (const __attribute__((address_space(1))) unsigned int*)g,
        (__attribute__((address_space(3))) unsigned int*)l,
        16, 0, 0);
}

// bytes {0,1} -> {+1, -1(0xFF)}; no cross-byte carries.
__device__ __forceinline__ unsigned int to_pm1(unsigned int c) {
    return c + ((c ^ 0x01010101u) * 255u);
}

// Fused packing, 768 blocks x 512 threads.
// blocks [0,256): x -> x8f, LDS-staged. Block (rb=b>>2, kq=b&3): rows
//   rb*32..+31, k-bytes [kq*1024,+1024) (kps kq*32..+31).
// blocks [256,768): masks -> m8Tf, 2 tiles per block (R17 tile math).
__global__ __launch_bounds__(512)
void pack_all(const int* __restrict__ x,
              const void* __restrict__ mraw,
              char* __restrict__ x8f,
              char* __restrict__ m8Tf) {
    __shared__ __align__(16) char buf[34816];
    const int tid = threadIdx.x;
    if (blockIdx.x < 256) {
        const int rb = blockIdx.x >> 2;            // 0..63
        const int kq = blockIdx.x & 3;             // k quarter
        unsigned int (*tlx)[260] = (unsigned int (*)[260])buf;
        const int sub = tid >> 8;                  // 0/1
        const int t2  = tid & 255;                 // int4 index in fragment

        // stage 1: 16 iters x 2 rows; per instr each wave reads 64
        // consecutive int4 = 1KB contiguous of one row fragment.
        const int4* src4 = (const int4*)x;
        #pragma unroll
        for (int i = 0; i < 16; ++i) {
            const int rl  = i * 2 + sub;           // row local 0..31
            const int row = rb * 32 + rl;
            int4 v = src4[(size_t)row * 1024 + kq * 256 + t2];
            unsigned int t = (unsigned int)(v.x & 1) |
                             ((unsigned int)(v.y & 1) << 8) |
                             ((unsigned int)(v.z & 1) << 16) |
                             ((unsigned int)(v.w & 1) << 24);
            tlx[rl][t2] = to_pm1(t);               // u32 = packed bytes 4*t2..+3
        }
        __syncthreads();

        // stage 2: 8 waves x 4 kps; lane l = chunk slot (row l&31, half l>>5);
        // wave store = one contiguous 1KB frag chunk.
        const int l = tid & 63;
        const int w = tid >> 6;                    // 0..7
        #pragma unroll
        for (int j = 0; j < 4; ++j) {
            const int kpl = w * 4 + j;             // 0..31
            uint4 v = *(const uint4*)&tlx[l & 31][kpl * 8 + (l >> 5) * 4];
            *(uint4*)(x8f + (size_t)rb * 131072 +
                      (size_t)(kq * 32 + kpl) * 1024 + l * 16) = v;
        }
    } else {
        // two 64(n) x 256(k) tiles in parallel: sub-block 0/1.
        const int sub = tid >> 8;                  // 0/1
        const int t2  = tid & 255;
        const int tile = (blockIdx.x - 256) * 2 + sub;  // 0..1023
        const int n0 = (tile >> 4) * 64;
        const int k0 = (tile & 15) * 256;
        unsigned int (*tl)[68] = (unsigned int (*)[68])(buf + sub * 17408);

        // dtype detect (u8-bool vs int32), exact: int32 words are {0,1};
        // u8-bool words exceed 1 unless bytes 1-3 all zero (P ~ 8^-64/wave).
        const unsigned char* mb = (const unsigned char*)mraw;
        const unsigned int pv = *(const unsigned int*)(mb + (t2 & 63) * 4);
        const bool isU8 = __any(pv > 1u);

        // stage 1: thread reads 4 k-rows x 16 n-cols (16B/lane coalesced).
        const int kq4  = t2 >> 2;                  // 0..63: k-quad index
        const int nq16 = (t2 & 3) * 16;            // n-group base
        unsigned int b[4][4];                      // [k-row r][n-word w]
        if (isU8) {
            #pragma unroll
            for (int r = 0; r < 4; ++r) {
                uint4 v = *(const uint4*)(mb + (size_t)(k0 + kq4 * 4 + r) * DOUT
                                          + n0 + nq16);
                b[r][0] = v.x; b[r][1] = v.y; b[r][2] = v.z; b[r][3] = v.w;
            }
        } else {
            const int4* m32 = (const int4*)mraw;
            #pragma unroll
            for (int r = 0; r < 4; ++r)
                #pragma unroll
                for (int q = 0; q < 4; ++q) {
                    int4 v = m32[((size_t)(k0 + kq4 * 4 + r) * DOUT
                                  + n0 + nq16 + q * 4) >> 2];
                    b[r][q] = (unsigned int)(v.x & 1) |
                              ((unsigned int)(v.y & 1) << 8) |
                              ((unsigned int)(v.z & 1) << 16) |
                              ((unsigned int)(v.w & 1) << 24);
                }
        }
        // transpose each 4x4 byte block via v_perm (verified recipe), ±1,
        // write n-major into LDS: word [n][kq4] = bytes k=k0+kq4*4..+3.
        #pragma unroll
        for (int w = 0; w < 4; ++w) {
            unsigned int a0 = b[0][w], a1 = b[1][w], a2 = b[2][w], a3 = b[3][w];
            unsigned int x0 = __builtin_amdgcn_perm(a1, a0, 0x05010400u);
            unsigned int x1 = __builtin_amdgcn_perm(a3, a2, 0x05010400u);
            unsigned int x2 = __builtin_amdgcn_perm(a1, a0, 0x07030602u);
            unsigned int x3 = __builtin_amdgcn_perm(a3, a2, 0x07030602u);
            unsigned int c0 = __builtin_amdgcn_perm(x1, x0, 0x05040100u);
            unsigned int c1 = __builtin_amdgcn_perm(x1, x0, 0x07060302u);
            unsigned int c2 = __builtin_amdgcn_perm(x3, x2, 0x05040100u);
            unsigned int c3 = __builtin_amdgcn_perm(x3, x2, 0x07060302u);
            tl[nq16 + w * 4 + 0][kq4] = to_pm1(c0);
            tl[nq16 + w * 4 + 1][kq4] = to_pm1(c1);
            tl[nq16 + w * 4 + 2][kq4] = to_pm1(c2);
            tl[nq16 + w * 4 + 3][kq4] = to_pm1(c3);
        }
        __syncthreads();

        // stage 2: frag-major out. Wave wvp writes chunks idx = wvp*4+j:
        // nb-local = idx>>3, kp-local = idx&7. Lane l holds
        // (n = nb*32 + (l&31), k-half l>>5) -> 16B; 1KB coalesced per chunk.
        const int l   = t2 & 63;
        const int wvp = t2 >> 6;
        #pragma unroll
        for (int j = 0; j < 4; ++j) {
            const int idxc = wvp * 4 + j;          // 0..15
            const int nbl  = idxc >> 3;            // 0..1
            const int kpl  = idxc & 7;             // 0..7
            uint4 v = *(const uint4*)&tl[nbl * 32 + (l & 31)]
                                       [kpl * 8 + (l >> 5) * 4];
            const size_t off = (size_t)((n0 >> 5) + nbl) * 131072 +
                               (size_t)((k0 >> 5) + kpl) * 1024 + l * 16;
            *(uint4*)(m8Tf + off) = v;
        }
    }
}

// i8 MFMA GEMM (R21 verbatim): 256(m)x128(n) block tile, 8 waves =
// 2m x 2n x 2k(split-K), wave tile 128x64 (acc[4][2]). BK=128 chunks (32),
// triple-buffer LDS (144 KB), depth-2 prefetch, one raw s_barrier per chunk
// with counted vmcnt(6). Split-K combine via LDS pool. bm = flat&7 = XCD.
__global__ __launch_bounds__(512)
void bgemm(const char* __restrict__ x8f,
           const char* __restrict__ m8Tf,
           const int* __restrict__ thr,
           int* __restrict__ out) {
    const int flat = blockIdx.x;                   // 0..255
    const int bm   = flat & 7;                     // XCD id = A panel
    const int bn   = flat >> 3;                    // 0..31
    const int b0   = bm * 256;                     // m
    const int o0   = bn * 128;                     // n

    const int tid  = threadIdx.x;
    const int lane = tid & 63;
    const int wv   = tid >> 6;           // 0..7
    const int im   = wv & 1;
    const int in_  = (wv >> 1) & 1;
    const int kh   = wv >> 2;            // split-K half
    const int wm   = im * 128;           // wave tile m origin
    const int wn   = in_ * 64;           // wave tile n origin
    const int l31  = lane & 31;
    const int lh   = lane >> 5;

    // 3 buffers x (A 32KB + B 16KB) = 144 KB; pool reused for split-K combine.
    __shared__ __align__(16) char lds[3 * 49152];

    // stage chunk-step c -> buf: 48 x 1KB frag chunks, all linear.
    // 6 global_load_lds per thread (A:4, B:2).
    auto stage = [&](int c, int buf) {
        char* bufA = lds + buf * 49152;
        char* bufB = bufA + 32768;
        const int kp0 = c * 4;
        #pragma unroll
        for (int j = 0; j < 4; ++j) {              // A: 4 chunks/wave
            const int ci = wv * 4 + j;             // 0..31
            const int rb = ci >> 2, kp = ci & 3;
            async_load16(x8f + (size_t)(bm * 8 + rb) * 131072 +
                               (size_t)(kp0 + kp) * 1024 + lane * 16,
                         bufA + ci * 1024 + lane * 16);
        }
        #pragma unroll
        for (int j = 0; j < 2; ++j) {              // B: 2 chunks/wave
            const int ci = wv * 2 + j;             // 0..15
            const int nb = ci >> 2, kp = ci & 3;
            async_load16(m8Tf + (size_t)(bn * 4 + nb) * 131072 +
                                (size_t)(kp0 + kp) * 1024 + lane * 16,
                         bufB + ci * 1024 + lane * 16);
        }
    };

    v16i acc[4][2];
    #pragma unroll
    for (int t = 0; t < 4; ++t)
        #pragma unroll
        for (int u = 0; u < 2; ++u)
            acc[t][u] = (v16i)(0);

    // prologue: depth-2 prefetch (12 loads/thread in flight).
    stage(0, 0);
    stage(1, 1);

    for (int c = 0; c < 32; ++c) {
        // drain exactly stage(c): leave stage(c+1) (6 loads) in flight.
        if (c < 31) asm volatile("s_waitcnt vmcnt(6)" ::: "memory");
        else        asm volatile("s_waitcnt vmcnt(0)" ::: "memory");
        __builtin_amdgcn_s_barrier();  // stage(c) visible everywhere; all
                                       // waves done computing c-1 -> buf free
        if (c < 30) stage(c + 2, (c + 2) % 3);

        const char* bufA = lds + (c % 3) * 49152;
        const char* bufB = bufA + 32768;
        #pragma unroll
        for (int ks = 0; ks < 2; ++ks) {
            const int kp = kh * 2 + ks;            // this wave's kp chunk
            v4i aF[4], bF[2];
            #pragma unroll
            for (int t = 0; t < 4; ++t)
                aF[t] = *(const v4i*)&bufA[((im * 4 + t) * 4 + kp) * 1024
                                           + lane * 16];
            #pragma unroll
            for (int u = 0; u < 2; ++u)
                bF[u] = *(const v4i*)&bufB[((in_ * 2 + u) * 4 + kp) * 1024
                                           + lane * 16];
            #pragma unroll
            for (int t = 0; t < 4; ++t)
                #pragma unroll
                for (int u = 0; u < 2; ++u)
                    acc[t][u] = __builtin_amdgcn_mfma_i32_32x32x32_i8(
                        aF[t], bF[u], acc[t][u], 0, 0, 0);
        }
    }
    __syncthreads();   // all compute done; lds pool free for combine

    // ---- split-K combine. Pair p = (im,in_): waves (p, kh=0) and (p, kh=1)
    // computed the same 128x64 tile over disjoint K halves. Each wave gives
    // one 64-row half via LDS and keeps the other: h=0 keeps t0,1 gives t2,3;
    // h=1 keeps t2,3 gives t0,1. Pool: per pair 8192 i32 (2 halves x 4096).
    int* pool = (int*)lds;                         // 128 KB used
    const int p = wv & 3;
    {
        const int give0 = kh ? 0 : 2;              // first given t
        const int bw_ = p * 8192 + (kh ? 0 : 1) * 4096;
        #pragma unroll
        for (int tt = 0; tt < 2; ++tt) {
            const int t = give0 + tt;
            #pragma unroll
            for (int u = 0; u < 2; ++u)
                #pragma unroll
                for (int r = 0; r < 16; ++r) {
                    const int rowl = (r & 3) + 8 * (r >> 2) + 4 * lh;
                    pool[bw_ + (tt * 32 + rowl) * 64 + u * 32 + l31] = acc[t][u][r];
                }
        }
    }
    __syncthreads();
    const int keep0 = kh ? 2 : 0;
    const int br_ = p * 8192 + kh * 4096;          // partner's gift = my kept rows
    #pragma unroll
    for (int tt = 0; tt < 2; ++tt) {
        const int t = keep0 + tt;
        #pragma unroll
        for (int u = 0; u < 2; ++u)
            #pragma unroll
            for (int r = 0; r < 16; ++r) {
                const int rowl = (r & 3) + 8 * (r >> 2) + 4 * lh;
                acc[t][u][r] += pool[br_ + (tt * 32 + rowl) * 64 + u * 32 + l31];
            }
    }

    // epilogue: out = (dot± > 2*thr - 4096).
    // C/D layout (verified R7): col = lane&31; row = (reg&3)+8*(reg>>2)+4*(lane>>5).
    #pragma unroll
    for (int u = 0; u < 2; ++u) {
        const int o   = o0 + wn + u * 32 + l31;
        const int lim = 2 * thr[o] - DIN;
        #pragma unroll
        for (int tt = 0; tt < 2; ++tt) {
            const int t = keep0 + tt;
            #pragma unroll
            for (int r = 0; r < 16; ++r) {
                const int rowl = (r & 3) + 8 * (r >> 2) + 4 * lh;
                const int b    = b0 + wm + kh * 64 + tt * 32 + rowl;
                out[(size_t)b * DOUT + o] = (acc[t][u][r] > lim) ? 1 : 0;
            }
        }
    }
}

extern "C" void kernel_launch(void* const* d_in, const int* in_sizes, int n_in,
                              void* d_out, int out_size, void* d_ws, size_t ws_size,
                              hipStream_t stream) {
    const int* x          = (const int*)d_in[0];
    const void* masks     = d_in[1];           // bool: u8 or int32 (detected inline)
    const int* thresholds = (const int*)d_in[2];
    int* out              = (int*)d_out;

    char* x8f  = (char*)d_ws;                         // 8 MB frag-major
    char* m8Tf = (char*)d_ws + ((size_t)8 << 20);     // 16 MB frag-major

    pack_all<<<768, 512, 0, stream>>>(x, masks, x8f, m8Tf);
    bgemm<<<256, 512, 0, stream>>>(x8f, m8Tf, thresholds, out);
}